// Round 7
// baseline (153.834 us; speedup 1.0000x reference)
//
#include <hip/hip_runtime.h>
#include <hip/hip_bf16.h>
#include <stdint.h>

// cheb_conv_with_Att_static: out[b,t,v,c] = relu( sum_{k,f} theta[k,f,c] *
//     sum_u cheb[k,u,v]*Att[b,u,v]*x[b,t,u,f] )
// B=8 T=12 V=2048 F=16 K=3 C=64
#define B_  8
#define T_  12
#define V_  2048
#define F_  16
#define K_  3
#define C_  64
#define N_  192   // T*F

typedef _Float16 f16;
typedef _Float16 half2v __attribute__((ext_vector_type(2)));
typedef _Float16 half4v __attribute__((ext_vector_type(4)));
typedef _Float16 half8v __attribute__((ext_vector_type(8)));
typedef float    f32x4  __attribute__((ext_vector_type(4)));
typedef unsigned int u32;

// ---------------------------------------------------------------------------
// Kernel 1a: XT[b][n=t*16+f][u] = (f16) x[b][t][u][f]   (u becomes contiguous)
// ---------------------------------------------------------------------------
__global__ __launch_bounds__(256) void prep_xt(const float* __restrict__ x,
                                               f16* __restrict__ XT) {
  int bid = blockIdx.x;
  int bt = bid >> 2, uc = bid & 3;
  int b = bt / T_, t = bt % T_;
  __shared__ float tile[64][17];
  int r  = threadIdx.x >> 2, fq = threadIdx.x & 3;   // load mapping
  int f  = threadIdx.x >> 4, uq = threadIdx.x & 15;  // store mapping
  for (int u0 = uc * 512; u0 < uc * 512 + 512; u0 += 64) {
    f32x4 v = *(const f32x4*)(x + ((size_t)(b * T_ + t) * V_ + u0 + r) * F_ + fq * 4);
    tile[r][fq * 4 + 0] = v[0];
    tile[r][fq * 4 + 1] = v[1];
    tile[r][fq * 4 + 2] = v[2];
    tile[r][fq * 4 + 3] = v[3];
    __syncthreads();
    half4v h;
    h[0] = (f16)tile[uq * 4 + 0][f];
    h[1] = (f16)tile[uq * 4 + 1][f];
    h[2] = (f16)tile[uq * 4 + 2][f];
    h[3] = (f16)tile[uq * 4 + 3][f];
    *(half4v*)(XT + (size_t)(b * N_ + t * F_ + f) * V_ + u0 + uq * 4) = h;
    __syncthreads();
  }
}

// ---------------------------------------------------------------------------
// Kernel 1b: chebT = f16 transpose of cheb, blocked for 16x16x32 A-frags:
//   elem(k,v,u) at (((k*128 + (v>>4))*256 + (u>>3))*16 + (v&15))*8 + (u&7)
// A wave-fragment (16 v-rows x 32 u, lane l: v=(l&15), u=(l>>4)*8..+8) is
// 1 KB CONTIGUOUS per wave -> single coalesced 16B/lane load.
// ---------------------------------------------------------------------------
__global__ __launch_bounds__(256) void prep_chebT(const float* __restrict__ c,
                                                  f16* __restrict__ cT) {
  int bid = blockIdx.x;
  int vt = bid & 31, ut = (bid >> 5) & 31, k = bid >> 10;
  int u0 = ut * 64, v0 = vt * 64;
  __shared__ float tile[64][68];
  int tid = threadIdx.x;
  int lr = tid >> 4, lc = (tid & 15) * 4;
  const float* src = c + ((size_t)k * V_ + u0) * V_ + v0;
#pragma unroll
  for (int i = 0; i < 4; ++i) {
    f32x4 v = *(const f32x4*)(src + (size_t)(lr + 16 * i) * V_ + lc);
    tile[lr + 16 * i][lc + 0] = v[0];
    tile[lr + 16 * i][lc + 1] = v[1];
    tile[lr + 16 * i][lc + 2] = v[2];
    tile[lr + 16 * i][lc + 3] = v[3];
  }
  __syncthreads();
  int vl = tid & 63, uc0 = tid >> 6;
#pragma unroll
  for (int i = 0; i < 2; ++i) {
    int uc = uc0 + 4 * i;                 // u-chunk 0..7
    half8v h;
#pragma unroll
    for (int j = 0; j < 8; ++j) h[j] = (f16)tile[uc * 8 + j][vl];
    int vb16 = vt * 4 + (vl >> 4);        // v>>4
    int vi   = vl & 15;
    int ub8  = ut * 8 + uc;               // u>>3
    size_t off = ((((size_t)k * 128 + vb16) * 256 + ub8) * 16 + vi) * 8;
    *(half8v*)(cT + off) = h;
  }
}

// ---------------------------------------------------------------------------
// Kernel 2 (round-7, occupancy-first): per (b,vt32,nh,uh), all 3 k:
//   rhs[b][t][v][uh*48+k*16+f] = sum_{u in half} (cheb*Att) * XT
// BM=32, BN=96, BK=64, 4 waves (2v x 2n), wave tile 16v x 48n, 16x16x32 MFMA.
// acc = 3k x 3n x f32x4 = 36 AGPR; target total <=128 -> 4 waves/EU,
// 4 blocks/CU (16 waves/CU).  LDS 32KB: B 12K dbuf + att-f16 4K dbuf.
// cheb A-frags load directly from blocked chebT (1KB/wave contiguous, L2-hot
// via XCD pin bid%8==vt%8; nh-pair shares att+cheb on same XCD).
// One barrier per step; att reg-transposed (2 x f32x4 transient) into alt buf.
// ---------------------------------------------------------------------------
#define MFMA16(a, b, c) __builtin_amdgcn_mfma_f32_16x16x32_f16(a, b, c, 0, 0, 0)

#define KS_STEP(ks, AC, BC, tt)                                                 \
  {                                                                             \
    const int kb = (ks) * 64 + lg * 16;                                         \
    half8v b0 = *(const half8v*)((BC) + n0 * 128 + (kb ^ bk0));                 \
    half8v b1 = *(const half8v*)((BC) + n1 * 128 + (kb ^ bk1));                 \
    half8v b2 = *(const half8v*)((BC) + n2 * 128 + (kb ^ bk2));                 \
    half8v af = *(const half8v*)((AC) + vr * 128 + (kb ^ ak));                  \
    const size_t co = (size_t)((tt) * 8 + (ks) * 4) * 128;                      \
    _Pragma("unroll")                                                           \
    for (int k = 0; k < 3; ++k) {                                               \
      half8v cf = *(const half8v*)(chb[k] + co);                                \
      half8v a = cf * af;                                                       \
      __builtin_amdgcn_s_setprio(1);                                            \
      acc[k][0] = MFMA16(a, b0, acc[k][0]);                                     \
      acc[k][1] = MFMA16(a, b1, acc[k][1]);                                     \
      acc[k][2] = MFMA16(a, b2, acc[k][2]);                                     \
      __builtin_amdgcn_s_setprio(0);                                            \
    }                                                                           \
  }

template<int UH>
__global__ __launch_bounds__(256, 4) void gemm3(const float* __restrict__ Att,
                                                const f16* __restrict__ chebT,
                                                const f16* __restrict__ XT,
                                                f16* __restrict__ rhs) {
  constexpr int NSTEP = (V_ / UH) / 64;
  const int bid = blockIdx.x;
  const int vt = (bid & 7) | (((bid >> 3) & 7) << 3);   // 0..63, vt%8 = XCD
  const int r2 = bid >> 6;
  const int nh = r2 & 1;
  const int r3 = r2 >> 1;
  const int uh = r3 % UH;
  const int b  = r3 / UH;
  const int vbase = vt * 32;
  const size_t ubase = (size_t)uh * (V_ / UH);

  __shared__ char smem[32768];          // B0 12K | B1 12K | A0 4K | A1 4K
  char* Bb0 = smem;
  char* Bb1 = smem + 12288;
  char* Ab0 = smem + 24576;
  char* Ab1 = smem + 28672;

  const int tid = threadIdx.x;
  const int wave = tid >> 6, lane = tid & 63;
  const int wv = wave >> 1, wn = wave & 1;
  const int l15 = lane & 15, lg = lane >> 4;

  // A-frag (att product): v-row + swizzle key
  const int vr = wv * 16 + l15;
  const int ak = (vr & 7) << 4;
  // B-frags: 3 n-subtiles
  const int n0 = wn * 48 + l15, n1 = n0 + 16, n2 = n0 + 32;
  const int bk0 = (n0 & 7) << 4, bk1 = (n1 & 7) << 4, bk2 = (n2 & 7) << 4;

  // cheb lane base pointers (one per k)
  const int vb16 = vt * 2 + wv;
  const f16* chb[3];
#pragma unroll
  for (int k = 0; k < 3; ++k)
    chb[k] = chebT + ((((size_t)k * 128 + vb16) * 256 + (ubase >> 3)) * 16) * 8
           + lg * 128 + l15 * 8;

  // att staging: thread covers 4v x 2u
  const int vsub = (tid & 7) * 4;
  const int usub = (tid >> 3) * 2;       // 0..62
  const float* attb = Att + (size_t)b * V_ * V_ + (ubase + usub) * V_ + vbase + vsub;

  // B glds: 12 slots x 1KB, 3 per wave
  const f16* xtb = XT + (size_t)b * N_ * V_ + (size_t)(nh * 96) * V_ + ubase;
  const int gl_c = lane & 7;

  f32x4 acc[3][3];
#pragma unroll
  for (int k = 0; k < 3; ++k)
#pragma unroll
    for (int ni = 0; ni < 3; ++ni) acc[k][ni] = 0;

  auto stageB = [&](int t, char* Bb) {
#pragma unroll
    for (int e = 0; e < 3; ++e) {
      int slot = wave * 3 + e;
      int n = slot * 8 + (lane >> 3);
      int cc = gl_c ^ (n & 7);
      const f16* src = xtb + (size_t)n * V_ + t * 64 + cc * 8;
      __builtin_amdgcn_global_load_lds((const __attribute__((address_space(1))) u32*)src,
                                       (__attribute__((address_space(3))) u32*)(Bb + slot * 1024),
                                       16, 0, 0);
    }
  };
  auto writeAtt = [&](const f32x4& p0, const f32x4& p1, char* Aw) {
#pragma unroll
    for (int j = 0; j < 4; ++j) {
      int v2 = vsub + j;
      half2v h;
      h[0] = (f16)p0[j]; h[1] = (f16)p1[j];
      *(half2v*)(Aw + v2 * 128 + ((usub * 2) ^ ((v2 & 7) << 4))) = h;
    }
  };

  // ---- prologue: stage step 0 ----
  {
    f32x4 p0 = *(const f32x4*)(attb);
    f32x4 p1 = *(const f32x4*)(attb + V_);
    stageB(0, Bb0);
    writeAtt(p0, p1, Ab0);
  }
  __syncthreads();

#pragma unroll 1
  for (int t = 0; t < NSTEP; ++t) {
    char* Bc = (t & 1) ? Bb1 : Bb0;
    char* Bn = (t & 1) ? Bb0 : Bb1;
    char* Ac = (t & 1) ? Ab1 : Ab0;
    char* An = (t & 1) ? Ab0 : Ab1;
    const bool pref = (t + 1) < NSTEP;

    f32x4 p0, p1;
    if (pref) {
      p0 = *(const f32x4*)(attb + (size_t)((t + 1) * 64) * V_);
      p1 = *(const f32x4*)(attb + (size_t)((t + 1) * 64 + 1) * V_);
      stageB(t + 1, Bn);
    }

    KS_STEP(0, Ac, Bc, t)
    KS_STEP(1, Ac, Bc, t)

    if (pref) writeAtt(p0, p1, An);
    __syncthreads();
  }

  // ---- epilogue: scatter acc -> rhs[b][t][v][uh*48 + k*16 + f] (f16) ----
#pragma unroll
  for (int ni = 0; ni < 3; ++ni) {
    int n = nh * 96 + wn * 48 + ni * 16 + l15;
    int tt = n >> 4, fi = n & 15;
#pragma unroll
    for (int k = 0; k < 3; ++k) {
#pragma unroll
      for (int r = 0; r < 4; ++r) {
        int v = vbase + wv * 16 + lg * 4 + r;
        rhs[((size_t)(b * T_ + tt) * V_ + v) * (48 * UH) + uh * 48 + k * 16 + fi] =
            (f16)acc[k][ni][r];
      }
    }
  }
}

// ---------------------------------------------------------------------------
// Kernel 3: out[row, c] = relu( sum_{s} rhs[row][s*16+..] * theta[(s%3)*16+..][c] )
// ---------------------------------------------------------------------------
template<int UH>
__global__ __launch_bounds__(256) void epi(const f16* __restrict__ rhs,
                                           const float* __restrict__ theta,
                                           float* __restrict__ out) {
  int wave = threadIdx.x >> 6, lane = threadIdx.x & 63;
  int row0 = blockIdx.x * 128 + wave * 32;
  int cl = lane & 31, kh = (lane >> 5) * 8;

  half8v bf[2][3];
#pragma unroll
  for (int nf = 0; nf < 2; ++nf)
#pragma unroll
    for (int ks = 0; ks < 3; ++ks) {
      half8v hb;
#pragma unroll
      for (int j = 0; j < 8; ++j)
        hb[j] = (f16)theta[(size_t)(ks * 16 + kh + j) * C_ + nf * 32 + cl];
      bf[nf][ks] = hb;
    }

  typedef float f32x16 __attribute__((ext_vector_type(16)));
  f32x16 acc0 = 0, acc1 = 0;
#pragma unroll
  for (int s = 0; s < 3 * UH; ++s) {
    half8v a = *(const half8v*)(rhs + (size_t)(row0 + cl) * (48 * UH) + s * 16 + kh);
    acc0 = __builtin_amdgcn_mfma_f32_32x32x16_f16(a, bf[0][s % 3], acc0, 0, 0, 0);
    acc1 = __builtin_amdgcn_mfma_f32_32x32x16_f16(a, bf[1][s % 3], acc1, 0, 0, 0);
  }
#pragma unroll
  for (int r = 0; r < 16; ++r) {
    int row = row0 + (r & 3) + 8 * (r >> 2) + 4 * (lane >> 5);
    out[(size_t)row * C_ + cl]      = fmaxf(acc0[r], 0.f);
    out[(size_t)row * C_ + 32 + cl] = fmaxf(acc1[r], 0.f);
  }
}

// ---------------------------------------------------------------------------
extern "C" void kernel_launch(void* const* d_in, const int* in_sizes, int n_in,
                              void* d_out, int out_size, void* d_ws, size_t ws_size,
                              hipStream_t stream) {
  const float* x     = (const float*)d_in[0];   // (8,12,2048,16)
  const float* Att   = (const float*)d_in[1];   // (8,2048,2048)
  const float* cheb  = (const float*)d_in[2];   // (3,2048,2048)
  const float* theta = (const float*)d_in[3];   // (3,16,64)
  float* out = (float*)d_out;                   // (8,12,2048,64) fp32

  const size_t xtB   = (size_t)B_ * N_ * V_ * sizeof(f16);        // 6.29 MB
  const size_t rhs2B = (size_t)B_ * T_ * V_ * 96 * sizeof(f16);   // 37.7 MB
  const size_t rhs1B = rhs2B / 2;                                 // 18.9 MB
  const size_t chB   = (size_t)K_ * V_ * V_ * sizeof(f16);        // 25.2 MB

  f16* XT = (f16*)d_ws;
  prep_xt<<<B_ * T_ * 4, 256, 0, stream>>>(x, XT);

  if (ws_size >= xtB + rhs2B + chB) {
    f16* rhs = (f16*)((char*)d_ws + xtB);
    f16* cT  = (f16*)((char*)d_ws + xtB + rhs2B);
    prep_chebT<<<K_ * 32 * 32, 256, 0, stream>>>(cheb, cT);
    gemm3<2><<<B_ * 64 * 2 * 2, 256, 0, stream>>>(Att, cT, XT, rhs);
    epi<2><<<(B_ * T_ * V_) / 128, 256, 0, stream>>>(rhs, theta, out);
  } else {
    f16* rhs = (f16*)((char*)d_ws + xtB);
    f16* cT  = (f16*)((char*)d_ws + xtB + rhs1B);
    prep_chebT<<<K_ * 32 * 32, 256, 0, stream>>>(cheb, cT);
    gemm3<1><<<B_ * 64 * 2 * 1, 256, 0, stream>>>(Att, cT, XT, rhs);
    epi<1><<<(B_ * T_ * V_) / 128, 256, 0, stream>>>(rhs, theta, out);
  }
}

// Round 8
// 114.224 us; speedup vs baseline: 1.3468x; 1.3468x over previous
//
#include <hip/hip_runtime.h>
#include <hip/hip_bf16.h>
#include <stdint.h>

// cheb_conv_with_Att_static: out[b,t,v,c] = relu( sum_{k,f} theta[k,f,c] *
//     sum_u cheb[k,u,v]*Att[b,u,v]*x[b,t,u,f] )
// B=8 T=12 V=2048 F=16 K=3 C=64
#define B_  8
#define T_  12
#define V_  2048
#define F_  16
#define K_  3
#define C_  64
#define N_  192   // T*F

typedef _Float16 f16;
typedef _Float16 half4v __attribute__((ext_vector_type(4)));
typedef _Float16 half8v __attribute__((ext_vector_type(8)));
typedef float    f32x4  __attribute__((ext_vector_type(4)));
typedef float    f32x16 __attribute__((ext_vector_type(16)));
typedef unsigned int u32;

// ---------------------------------------------------------------------------
// Kernel 1a: XT[b][n=t*16+f][u] = (f16) x[b][t][u][f]   (u becomes contiguous)
// ---------------------------------------------------------------------------
__global__ __launch_bounds__(256) void prep_xt(const float* __restrict__ x,
                                               f16* __restrict__ XT) {
  int bid = blockIdx.x;
  int bt = bid >> 2, uc = bid & 3;
  int b = bt / T_, t = bt % T_;
  __shared__ float tile[64][17];
  int r  = threadIdx.x >> 2, fq = threadIdx.x & 3;   // load mapping
  int f  = threadIdx.x >> 4, uq = threadIdx.x & 15;  // store mapping
  for (int u0 = uc * 512; u0 < uc * 512 + 512; u0 += 64) {
    f32x4 v = *(const f32x4*)(x + ((size_t)(b * T_ + t) * V_ + u0 + r) * F_ + fq * 4);
    tile[r][fq * 4 + 0] = v[0];
    tile[r][fq * 4 + 1] = v[1];
    tile[r][fq * 4 + 2] = v[2];
    tile[r][fq * 4 + 3] = v[3];
    __syncthreads();
    half4v h;
    h[0] = (f16)tile[uq * 4 + 0][f];
    h[1] = (f16)tile[uq * 4 + 1][f];
    h[2] = (f16)tile[uq * 4 + 2][f];
    h[3] = (f16)tile[uq * 4 + 3][f];
    *(half4v*)(XT + (size_t)(b * N_ + t * F_ + f) * V_ + u0 + uq * 4) = h;
    __syncthreads();
  }
}

// ---------------------------------------------------------------------------
// Kernel 1b: chebT = f16 transpose of cheb in fragment-native blocked layout:
//   elem(k,v,u) at ((((k*64 + (v>>5))*256 + (u>>3))*32 + (v&31))*8 + (u&7)
// so an MFMA A-fragment (8 contiguous u at fixed v, 32 consecutive v across
// lanes) is ONE coalesced 16B/lane load.
// ---------------------------------------------------------------------------
__global__ __launch_bounds__(256) void prep_chebT(const float* __restrict__ c,
                                                  f16* __restrict__ cT) {
  int bid = blockIdx.x;
  int vt = bid & 31, ut = (bid >> 5) & 31, k = bid >> 10;
  int u0 = ut * 64, v0 = vt * 64;
  __shared__ float tile[64][68];
  int tid = threadIdx.x;
  int lr = tid >> 4, lc = (tid & 15) * 4;
  const float* src = c + ((size_t)k * V_ + u0) * V_ + v0;
#pragma unroll
  for (int i = 0; i < 4; ++i) {
    f32x4 v = *(const f32x4*)(src + (size_t)(lr + 16 * i) * V_ + lc);
    tile[lr + 16 * i][lc + 0] = v[0];
    tile[lr + 16 * i][lc + 1] = v[1];
    tile[lr + 16 * i][lc + 2] = v[2];
    tile[lr + 16 * i][lc + 3] = v[3];
  }
  __syncthreads();
  int vl = tid & 63, uc0 = tid >> 6;
#pragma unroll
  for (int i = 0; i < 2; ++i) {
    int uc = uc0 + 4 * i;
    half8v h;
#pragma unroll
    for (int j = 0; j < 8; ++j) h[j] = (f16)tile[uc * 8 + j][vl];
    int vb = (v0 + vl) >> 5;
    int vi = vl & 31;
    size_t ut_idx = (size_t)(u0 >> 3) + uc;
    size_t off = ((((size_t)k * 64 + vb) * 256 + ut_idx) * 32 + vi) * 8;
    *(half8v*)(cT + off) = h;
  }
}

// ---------------------------------------------------------------------------
// Kernel 2 (round-8): round-6 structure + double-buffered REGISTER prefetch of
// the 12 cheb frags (cfA/cfB, statically named) + __launch_bounds__(256,1)
// so the full 512-reg/wave budget is usable at the locked 1-wave/SIMD point.
// Per step: issueAtt(t+1); stageB(t+1); loadCheb(t+1)->cf_next;
//           4x KS_GROUP on cf_cur (cheb already in regs: zero load stall);
//           writeAtt; barrier.
// ---------------------------------------------------------------------------
#define MFMA_H(a, b, c) __builtin_amdgcn_mfma_f32_32x32x16_f16(a, b, c, 0, 0, 0)

#define KS_GROUP(ks, AC, BC, CF)                                               \
  {                                                                            \
    const int kb = (ks) * 32 + hi * 16;                                        \
    half8v af = *(const half8v*)((AC) + vrow * 128 + (kb ^ skey));             \
    half8v b0 = *(const half8v*)((BC) + nrow0 * 128 + (kb ^ bk0));             \
    half8v b1 = *(const half8v*)((BC) + nrow1 * 128 + (kb ^ bk1));             \
    half8v b2 = *(const half8v*)((BC) + nrow2 * 128 + (kb ^ bk2));             \
    half8v a0 = CF[(ks) * 3 + 0] * af;                                         \
    half8v a1 = CF[(ks) * 3 + 1] * af;                                         \
    half8v a2 = CF[(ks) * 3 + 2] * af;                                         \
    __builtin_amdgcn_s_setprio(1);                                             \
    acc[0][0] = MFMA_H(a0, b0, acc[0][0]);                                     \
    acc[0][1] = MFMA_H(a0, b1, acc[0][1]);                                     \
    acc[0][2] = MFMA_H(a0, b2, acc[0][2]);                                     \
    acc[1][0] = MFMA_H(a1, b0, acc[1][0]);                                     \
    acc[1][1] = MFMA_H(a1, b1, acc[1][1]);                                     \
    acc[1][2] = MFMA_H(a1, b2, acc[1][2]);                                     \
    acc[2][0] = MFMA_H(a2, b0, acc[2][0]);                                     \
    acc[2][1] = MFMA_H(a2, b1, acc[2][1]);                                     \
    acc[2][2] = MFMA_H(a2, b2, acc[2][2]);                                     \
    __builtin_amdgcn_s_setprio(0);                                             \
  }

template<int UH>
__global__ __launch_bounds__(256, 1) void gemm4(const float* __restrict__ Att,
                                                const f16* __restrict__ chebT,
                                                const f16* __restrict__ XT,
                                                f16* __restrict__ rhs) {
  constexpr int NSTEP = (V_ / UH) / 64;   // 16 (UH=2) / 32 (UH=1)
  const int bid = blockIdx.x;
  const int vt = bid & 31;                // bid%8 == vt%8 -> XCD-pinned cheb slice
  const int rr = bid >> 5;
  const int b  = rr / UH;
  const int uh = rr % UH;
  const int vbase = vt * 64;
  const size_t ubase = (size_t)uh * (V_ / UH);

  __shared__ char smem[65536];            // B0 24K | B1 24K | A0 8K | A1 8K
  char* Bb0 = smem;
  char* Bb1 = smem + 24576;
  char* Ab0 = smem + 49152;
  char* Ab1 = smem + 57344;

  const int tid = threadIdx.x;
  const int wave = tid >> 6, lane = tid & 63;
  const int wm = wave >> 1, wn = wave & 1;
  const int hi = lane >> 5, l31 = lane & 31;
  const int vrow = wm * 32 + l31;
  const int vsub = (tid & 15) * 4, usub = (tid >> 4) * 4;

  const int skey = ((vrow + (vrow >> 3)) & 7) << 4;
  const int nrow0 = wn * 96 + l31;
  const int nrow1 = nrow0 + 32;
  const int nrow2 = nrow0 + 64;
  const int bk0 = (nrow0 & 7) << 4, bk1 = (nrow1 & 7) << 4, bk2 = (nrow2 & 7) << 4;

  // cheb lane base: frag (k, ks, t) = chb[k] + (t*8 + ks*2 + hi)*256  (elems)
  const int vb = vt * 2 + wm;
  const f16* chb0 = chebT + (((size_t)vb * 256 + (ubase >> 3)) * 32 + l31) * 8;
  const f16* chb1 = chb0 + (size_t)V_ * V_;
  const f16* chb2 = chb1 + (size_t)V_ * V_;

  const float* attb = Att + (size_t)b * V_ * V_ + (ubase + usub) * V_ + vbase + vsub;
  const f16*   xtb  = XT + (size_t)b * N_ * V_ + ubase;

  f32x16 acc[3][3];
#pragma unroll
  for (int k = 0; k < 3; ++k)
#pragma unroll
    for (int nf = 0; nf < 3; ++nf) acc[k][nf] = 0;

  f32x4 pa[4];
  const int gl_c = lane & 7;              // dest chunk; src chunk = gl_c^(n&7)

  auto stageB = [&](int t, char* Bb) {
#pragma unroll
    for (int e = 0; e < 6; ++e) {
      int slot = wave * 6 + e;
      int n = slot * 8 + (lane >> 3);
      int cc = gl_c ^ (n & 7);
      const f16* src = xtb + (size_t)n * V_ + t * 64 + cc * 8;
      __builtin_amdgcn_global_load_lds((const __attribute__((address_space(1))) u32*)src,
                                       (__attribute__((address_space(3))) u32*)(Bb + slot * 1024),
                                       16, 0, 0);
    }
  };
  auto issueAtt = [&](int t) {
#pragma unroll
    for (int i = 0; i < 4; ++i)
      pa[i] = *(const f32x4*)(attb + (size_t)(t * 64 + i) * V_);
  };
  auto writeAtt = [&](char* Aw) {
#pragma unroll
    for (int j = 0; j < 4; ++j) {
      int vr = vsub + j;
      half4v h;
      h[0] = (f16)pa[0][j]; h[1] = (f16)pa[1][j];
      h[2] = (f16)pa[2][j]; h[3] = (f16)pa[3][j];
      *(half4v*)(Aw + vr * 128 + ((usub * 2) ^ (((vr + (vr >> 3)) & 7) << 4))) = h;
    }
  };
  auto loadCheb = [&](int t, half8v cf[12]) {
#pragma unroll
    for (int ks = 0; ks < 4; ++ks) {
      const size_t co = (size_t)(t * 8 + ks * 2 + hi) * 256;
      cf[ks * 3 + 0] = *(const half8v*)(chb0 + co);
      cf[ks * 3 + 1] = *(const half8v*)(chb1 + co);
      cf[ks * 3 + 2] = *(const half8v*)(chb2 + co);
    }
  };

  half8v cfA[12], cfB[12];

  // ---- prologue: stage step 0 (LDS + cheb regs) ----
  issueAtt(0);
  stageB(0, Bb0);
  loadCheb(0, cfA);
  writeAtt(Ab0);
  __syncthreads();

#pragma unroll 1
  for (int t0 = 0; t0 < NSTEP; t0 += 2) {
    {
      // even phase: compute t0 from {Ab0,Bb0,cfA}; prefetch t0+1
      issueAtt(t0 + 1);
      stageB(t0 + 1, Bb1);
      loadCheb(t0 + 1, cfB);
      KS_GROUP(0, Ab0, Bb0, cfA)
      KS_GROUP(1, Ab0, Bb0, cfA)
      KS_GROUP(2, Ab0, Bb0, cfA)
      KS_GROUP(3, Ab0, Bb0, cfA)
      writeAtt(Ab1);
      __syncthreads();
    }
    {
      // odd phase: compute t0+1 from {Ab1,Bb1,cfB}; prefetch t0+2
      const bool p2 = (t0 + 2) < NSTEP;
      if (p2) {
        issueAtt(t0 + 2);
        stageB(t0 + 2, Bb0);
        loadCheb(t0 + 2, cfA);
      }
      KS_GROUP(0, Ab1, Bb1, cfB)
      KS_GROUP(1, Ab1, Bb1, cfB)
      KS_GROUP(2, Ab1, Bb1, cfB)
      KS_GROUP(3, Ab1, Bb1, cfB)
      if (p2) writeAtt(Ab0);
      __syncthreads();
    }
  }

  // ---- epilogue: scatter acc -> rhs[b][t][v][uh*48 + k*16 + f] (f16) ----
#pragma unroll
  for (int nf = 0; nf < 3; ++nf) {
    int n = wn * 96 + nf * 32 + l31;
    int tt = n >> 4, fi = n & 15;
#pragma unroll
    for (int k = 0; k < 3; ++k) {
#pragma unroll
      for (int r = 0; r < 16; ++r) {
        int v = vbase + wm * 32 + (r & 3) + 8 * (r >> 2) + 4 * hi;
        rhs[((size_t)(b * T_ + tt) * V_ + v) * (48 * UH) + uh * 48 + k * 16 + fi] =
            (f16)acc[k][nf][r];
      }
    }
  }
}

// ---------------------------------------------------------------------------
// Kernel 3: out[row, c] = relu( sum_{s} rhs[row][s*16+..] * theta[(s%3)*16+..][c] )
// ---------------------------------------------------------------------------
template<int UH>
__global__ __launch_bounds__(256) void epi(const f16* __restrict__ rhs,
                                           const float* __restrict__ theta,
                                           float* __restrict__ out) {
  int wave = threadIdx.x >> 6, lane = threadIdx.x & 63;
  int row0 = blockIdx.x * 128 + wave * 32;
  int cl = lane & 31, kh = (lane >> 5) * 8;

  half8v bf[2][3];
#pragma unroll
  for (int nf = 0; nf < 2; ++nf)
#pragma unroll
    for (int ks = 0; ks < 3; ++ks) {
      half8v hb;
#pragma unroll
      for (int j = 0; j < 8; ++j)
        hb[j] = (f16)theta[(size_t)(ks * 16 + kh + j) * C_ + nf * 32 + cl];
      bf[nf][ks] = hb;
    }

  f32x16 acc0 = 0, acc1 = 0;
#pragma unroll
  for (int s = 0; s < 3 * UH; ++s) {
    half8v a = *(const half8v*)(rhs + (size_t)(row0 + cl) * (48 * UH) + s * 16 + kh);
    acc0 = __builtin_amdgcn_mfma_f32_32x32x16_f16(a, bf[0][s % 3], acc0, 0, 0, 0);
    acc1 = __builtin_amdgcn_mfma_f32_32x32x16_f16(a, bf[1][s % 3], acc1, 0, 0, 0);
  }
#pragma unroll
  for (int r = 0; r < 16; ++r) {
    int row = row0 + (r & 3) + 8 * (r >> 2) + 4 * (lane >> 5);
    out[(size_t)row * C_ + cl]      = fmaxf(acc0[r], 0.f);
    out[(size_t)row * C_ + 32 + cl] = fmaxf(acc1[r], 0.f);
  }
}

// ---------------------------------------------------------------------------
extern "C" void kernel_launch(void* const* d_in, const int* in_sizes, int n_in,
                              void* d_out, int out_size, void* d_ws, size_t ws_size,
                              hipStream_t stream) {
  const float* x     = (const float*)d_in[0];   // (8,12,2048,16)
  const float* Att   = (const float*)d_in[1];   // (8,2048,2048)
  const float* cheb  = (const float*)d_in[2];   // (3,2048,2048)
  const float* theta = (const float*)d_in[3];   // (3,16,64)
  float* out = (float*)d_out;                   // (8,12,2048,64) fp32

  const size_t xtB   = (size_t)B_ * N_ * V_ * sizeof(f16);        // 6.29 MB
  const size_t rhs2B = (size_t)B_ * T_ * V_ * 96 * sizeof(f16);   // 37.7 MB
  const size_t rhs1B = rhs2B / 2;                                 // 18.9 MB
  const size_t chB   = (size_t)K_ * V_ * V_ * sizeof(f16);        // 25.2 MB

  f16* XT = (f16*)d_ws;
  prep_xt<<<B_ * T_ * 4, 256, 0, stream>>>(x, XT);

  if (ws_size >= xtB + rhs2B + chB) {
    f16* rhs = (f16*)((char*)d_ws + xtB);
    f16* cT  = (f16*)((char*)d_ws + xtB + rhs2B);
    prep_chebT<<<K_ * 32 * 32, 256, 0, stream>>>(cheb, cT);
    gemm4<2><<<B_ * 32 * 2, 256, 0, stream>>>(Att, cT, XT, rhs);
    epi<2><<<(B_ * T_ * V_) / 128, 256, 0, stream>>>(rhs, theta, out);
  } else {
    f16* rhs = (f16*)((char*)d_ws + xtB);
    f16* cT  = (f16*)((char*)d_ws + xtB + rhs1B);
    prep_chebT<<<K_ * 32 * 32, 256, 0, stream>>>(cheb, cT);
    gemm4<1><<<B_ * 32, 256, 0, stream>>>(Att, cT, XT, rhs);
    epi<1><<<(B_ * T_ * V_) / 128, 256, 0, stream>>>(rhs, theta, out);
  }
}